// Round 3
// baseline (459.988 us; speedup 1.0000x reference)
//
#include <hip/hip_runtime.h>

// Depthwise 1D conv (cross-correlation), SAME padding (pad_left = 4).
// x: (B=8, F=64, L=131072) f32 ; kernel: (F, 1, K=9) f32
// out: (F, B, 1, L) f32 -> out[(f*B + b)*L + l]
//
// v4: streaming + software pipeline. Evidence from v1-v3: block count and
// LDS-vs-direct are both non-factors; waves are stalled on memory latency
// (v2: Occupancy 80%, VALUBusy 9.7%). Fix the shape of the kernel: grid =
// 2048 blocks (exactly 8 blocks/CU resident, one dispatch wave), each block
// owns one row (weights + pointers set up once) and walks 32 chunks of 1024
// floats with a 2-stage pipeline: issue next chunk's 3 float4 loads, then
// compute+store the current chunk from resident registers. Steady state
// keeps 3 loads/thread in flight on top of full wave residency, and the
// store stream overlaps the load stream continuously -- copy-benchmark
// shape. Stores are nontemporal: out is never re-read, and bypassing L2/L3
// on writes preserves x's ~50% L3 residency (v2 measured FETCH=133MB of a
// 268MB input), keeping the read side L3-served.

#define BB 8
#define FF 64
#define LL 131072
#define KK 9
#define CHUNK 1024
#define CPR (LL / CHUNK)      // 128 chunks per row
#define NROWS (BB * FF)       // 512
#define BPR 4                 // blocks per row
#define GRID (NROWS * BPR)    // 2048 blocks = 8 per CU
#define ITERS (CPR / BPR)     // 32 chunks per block
#define STRIDE (BPR * CHUNK)  // 4096 floats between a block's chunks

typedef float __attribute__((ext_vector_type(4))) floatx4;

__device__ __forceinline__ void load_trio(const float* __restrict__ xrow,
                                          int l0, int t,
                                          float4& A, float4& B, float4& C)
{
    const int base  = l0 + 4 * t;
    const float* p  = xrow + base;
    if (l0 == 0 || l0 == (CPR - 1) * CHUNK) {
        // Row edge: halo float4s are 4-aligned -> fully in or fully out.
        A = (base - 4 >= 0) ? *(const float4*)(p - 4)
                            : make_float4(0.f, 0.f, 0.f, 0.f);
        B = *(const float4*)(p);
        C = (base + 7 < LL) ? *(const float4*)(p + 4)
                            : make_float4(0.f, 0.f, 0.f, 0.f);
    } else {
        A = *(const float4*)(p - 4);
        B = *(const float4*)(p);
        C = *(const float4*)(p + 4);
    }
}

__global__ __launch_bounds__(256) void dwconv1d_kernel(
    const float* __restrict__ x,
    const float* __restrict__ kern,
    float* __restrict__ out)
{
    const int n       = blockIdx.x;
    const int row_out = n >> 2;          // f*8 + b, in [0, 512)
    const int sub     = n & (BPR - 1);   // which chunk-lane of the row
    const int f       = row_out >> 3;
    const int b       = row_out & 7;

    const float* __restrict__ xrow = x + ((size_t)(b * FF + f)) * (size_t)LL;
    float* __restrict__ orow       = out + (size_t)row_out * (size_t)LL;

    const int t = threadIdx.x;

    // Weights: f is block-uniform -> scalar loads, loaded ONCE per block.
    float w[KK];
    #pragma unroll
    for (int k = 0; k < KK; ++k) w[k] = kern[f * KK + k];

    int l0 = sub * CHUNK;

    // Pipeline prologue: loads for chunk 0.
    float4 a0, b0, c0;
    load_trio(xrow, l0, t, a0, b0, c0);

    #pragma unroll 4
    for (int i = 0; i < ITERS; ++i) {
        const int l0n = l0 + STRIDE;

        // Issue next chunk's loads before touching current data.
        float4 a1, b1, c1;
        if (i + 1 < ITERS) load_trio(xrow, l0n, t, a1, b1, c1);

        // Compute current chunk (waits only on the loads issued last iter).
        const float xin[12] = { a0.x, a0.y, a0.z, a0.w,
                                b0.x, b0.y, b0.z, b0.w,
                                c0.x, c0.y, c0.z, c0.w };
        float acc[4];
        #pragma unroll
        for (int j = 0; j < 4; ++j) {
            float v0 = 0.f;
            #pragma unroll
            for (int k = 0; k < KK; ++k) v0 += w[k] * xin[j + k];
            acc[j] = v0;
        }
        floatx4 o = { acc[0], acc[1], acc[2], acc[3] };
        __builtin_nontemporal_store(o, (floatx4*)(orow + l0 + 4 * t));

        a0 = a1; b0 = b1; c0 = c1;
        l0 = l0n;
    }
}

extern "C" void kernel_launch(void* const* d_in, const int* in_sizes, int n_in,
                              void* d_out, int out_size, void* d_ws, size_t ws_size,
                              hipStream_t stream) {
    const float* x    = (const float*)d_in[0];
    const float* kern = (const float*)d_in[1];
    float* out        = (float*)d_out;

    hipLaunchKernelGGL(dwconv1d_kernel, dim3(GRID), dim3(256), 0, stream,
                       x, kern, out);
}

// Round 4
// 421.021 us; speedup vs baseline: 1.0926x; 1.0926x over previous
//
#include <hip/hip_runtime.h>

// Depthwise 1D conv (cross-correlation), SAME padding (pad_left = 4).
// x: (B=8, F=64, L=131072) f32 ; kernel: (F, 1, K=9) f32
// out: (F, B, 1, L) f32 -> out[(f*B + b)*L + l]
//
// v5: register-file halo exchange. Session evidence: v3/v4's direct-global
// form runs at the per-CU issued-VMEM ceiling (~10.5 B/cyc/CU = 6.4-7.0
// TB/s of ISSUED traffic) -- the 3x overlapping halo loads are NOT free
// even when they hit L1, because each load instruction consumes the CU's
// vector-memory issue/return slot at the same rate as HBM traffic. The
// LDS variants (v1/v2) dedup'd reads but paid 8-way bank conflicts
// (1.7e7 cycles) + a full-drain barrier instead.
//
// Fix: each thread loads EXACTLY its own float4 (1.0x reads); the +-4
// float halo comes from adjacent lanes via __shfl_up/__shfl_down
// (ds_bpermute: crossbar, no banks, no barrier, no LDS storage). Only
// the 2 wave-edge lanes (0 and 63) load their 16B halo directly ->
// issued read traffic 1.03x. Cross-lane + FMA cost (~110 cyc/wave/quad)
// is tiny vs the ~6400-cycle/quad memory budget -- stays memory-bound.
// Plain stores (NT stores regressed in v2 AND v4); 32k blocks, QPT=2
// (v3's proven dispatch shape); no persistent blocks (v4's L3-residency
// imbalance, Occupancy 80->65%).

#define BB 8
#define FF 64
#define LL 131072
#define KK 9
#define CHUNK 2048
#define CPR (LL / CHUNK)      // 64 chunks per row
#define CPR_SHIFT 6
#define NROWS (BB * FF)       // 512
#define QPT 2                 // output quads (4 floats) per thread

__global__ __launch_bounds__(256) void dwconv1d_kernel(
    const float* __restrict__ x,
    const float* __restrict__ kern,
    float* __restrict__ out)
{
    const int c       = blockIdx.x;
    const int chunk   = c & (CPR - 1);
    const int row_out = c >> CPR_SHIFT;   // f*8 + b, in [0, 512)
    const int f       = row_out >> 3;
    const int b       = row_out & 7;

    const float* __restrict__ xrow = x + ((size_t)(b * FF + f)) * (size_t)LL;
    float* __restrict__ orow       = out + (size_t)row_out * (size_t)LL;

    const int t    = threadIdx.x;
    const int lane = t & 63;
    const int l0   = chunk << 11;         // chunk * 2048

    // Main loads: thread t, quad q owns outputs [pos, pos+4). Always
    // fully in-bounds -- no checks, back-to-back issue.
    int pos[QPT];
    float4 m[QPT];
    #pragma unroll
    for (int q = 0; q < QPT; ++q) {
        pos[q] = l0 + 4 * t + 1024 * q;
        m[q]   = *(const float4*)(xrow + pos[q]);
    }

    // Wave-edge halo loads: lane 0 needs x[pos-4..pos-1] (left neighbor
    // wave's data), lane 63 needs x[pos+4..pos+7]. 4-aligned float4s:
    // fully in-bounds or fully zero (row ends only).
    float4 le[QPT], re[QPT];
    #pragma unroll
    for (int q = 0; q < QPT; ++q) {
        le[q] = make_float4(0.f, 0.f, 0.f, 0.f);
        re[q] = make_float4(0.f, 0.f, 0.f, 0.f);
    }
    if (lane == 0) {
        #pragma unroll
        for (int q = 0; q < QPT; ++q)
            if (pos[q] - 4 >= 0) le[q] = *(const float4*)(xrow + pos[q] - 4);
    }
    if (lane == 63) {
        #pragma unroll
        for (int q = 0; q < QPT; ++q)
            if (pos[q] + 7 < LL) re[q] = *(const float4*)(xrow + pos[q] + 4);
    }

    // Weights: f is block-uniform -> scalar loads, K$-resident.
    float w[KK];
    #pragma unroll
    for (int k = 0; k < KK; ++k) w[k] = kern[f * KK + k];

    #pragma unroll
    for (int q = 0; q < QPT; ++q) {
        // Halo from neighbor lanes through the crossbar.
        float4 L, R;
        L.x = __shfl_up(m[q].x, 1, 64);
        L.y = __shfl_up(m[q].y, 1, 64);
        L.z = __shfl_up(m[q].z, 1, 64);
        L.w = __shfl_up(m[q].w, 1, 64);
        R.x = __shfl_down(m[q].x, 1, 64);
        R.y = __shfl_down(m[q].y, 1, 64);
        R.z = __shfl_down(m[q].z, 1, 64);
        R.w = __shfl_down(m[q].w, 1, 64);
        if (lane == 0)  L = le[q];
        if (lane == 63) R = re[q];

        // Window x[pos-4 .. pos+7]; out[pos+j] = sum_k w[k]*x[pos+j-4+k].
        const float xin[12] = { L.x, L.y, L.z, L.w,
                                m[q].x, m[q].y, m[q].z, m[q].w,
                                R.x, R.y, R.z, R.w };
        float acc[4];
        #pragma unroll
        for (int j = 0; j < 4; ++j) {
            float v0 = 0.f;
            #pragma unroll
            for (int k = 0; k < KK; ++k) v0 += w[k] * xin[j + k];
            acc[j] = v0;
        }
        *(float4*)(orow + pos[q]) = make_float4(acc[0], acc[1], acc[2], acc[3]);
    }
}

extern "C" void kernel_launch(void* const* d_in, const int* in_sizes, int n_in,
                              void* d_out, int out_size, void* d_ws, size_t ws_size,
                              hipStream_t stream) {
    const float* x    = (const float*)d_in[0];
    const float* kern = (const float*)d_in[1];
    float* out        = (float*)d_out;

    const int grid  = NROWS * CPR;   // 32,768 blocks
    const int block = 256;

    hipLaunchKernelGGL(dwconv1d_kernel, dim3(grid), dim3(block), 0, stream,
                       x, kern, out);
}